// Round 9
// baseline (186.643 us; speedup 1.0000x reference)
//
#include <hip/hip_runtime.h>

// Depthwise 7x7 true-convolution (flipped kernel, SAME zero pad) + mish.
// x: [16,64,256,256] f32, kernel: [7,7] f32 (shared by all planes).
//
// Round-9: f16 LDS tile + v_dot2_f32_f16 (fp32 accumulate), tile 64w x 128h,
// 256 threads, thread = 8 cols x 4 rows (32 outputs). Input tile 134 rows x
// 72 halfs (9 granules of 16B), row stride 12 granules (192 B, 25.7 KB ->
// 6 blocks/CU). Window = 10 rows, 2 ds_read_b128 each; granule-group
// residue (12*lr+tx) mod 8 = tx + 4*(rr&1) -> uniform 8 lanes/residue =
// b128 hardware minimum, conflict-free with no swizzle.
// Math per (row, out-row): 4 dot2 x 8 cols; data pairs natural dwords (odd
// col) or alignbit dwords (even col); weight pairs uniform in SGPRs.
// Register budget waves_per_eu(5,6): enough VGPR (~85-100) to hoist LDS
// loads (round-8 lesson: (4,8) squeezed to 48 VGPR -> serialized
// read->align->dot2 chains, latency-bound), still 5-6 waves/EU.

#define HW 256
#define TILE_W 64
#define TILE_H 128
#define LR 134           // input rows: 128 + 6 halo
#define NG 9             // data granules per row (72 halfs)
#define NGP 12           // padded granule row stride (192 B)
#define NSLOT (LR * NG)  // 1206 staging granules

typedef __fp16 h2 __attribute__((ext_vector_type(2)));
union U32H2 { unsigned i; h2 h; };

__device__ __forceinline__ float fdot2u(unsigned a, unsigned b, float c) {
    U32H2 ua, ub; ua.i = a; ub.i = b;
    return __builtin_amdgcn_fdot2(ua.h, ub.h, c, false);
}

__device__ __forceinline__ float mish_f(float y) {
    float t = __expf(y);            // inf-safe: d -> inf -> 2/d -> 0 -> y*1
    float u = 1.0f + t;
    float d = __fmaf_rn(u, u, 1.0f);
    return y * (1.0f - __fdividef(2.0f, d));
}

__global__ __launch_bounds__(256)
__attribute__((amdgpu_waves_per_eu(5, 6)))
void dwconv7_mish_kernel(const float* __restrict__ x,
                         const float* __restrict__ kern,
                         float* __restrict__ out) {
    __shared__ uint4 smemU4[LR * NGP];   // 25,728 B

    const int tid = threadIdx.x;
    const int tx  = tid & 7;             // 8 strips x 8 cols = 64 wide
    const int ty  = tid >> 3;            // 32 quads -> 128 rows
    const int col0 = blockIdx.x * TILE_W;
    const int row0 = blockIdx.y * TILE_H;
    const int plane = blockIdx.z;        // b*64 + c

    const float* __restrict__ xp = x + (size_t)plane * (HW * HW);
    float* __restrict__ op = out + (size_t)plane * (HW * HW);

    // Flipped kernel, packed f16 pairs in SGPRs:
    // wA[p][t] = pack(kf[p][2t], kf[p][2t+1]), kf[p][q] = kern[6-p][6-q],
    // kf[p][7] := 0.
    unsigned wA[7][4];
    #pragma unroll
    for (int p = 0; p < 7; ++p) {
        #pragma unroll
        for (int t = 0; t < 4; ++t) {
            float lo = kern[(6 - p) * 7 + (6 - 2 * t)];
            float hi = (t < 3) ? kern[(6 - p) * 7 + (5 - 2 * t)] : 0.0f;
            U32H2 u; u.h = __builtin_amdgcn_cvt_pkrtz(lo, hi);
            wA[p][t] = __builtin_amdgcn_readfirstlane(u.i);
        }
    }

    // Stage input tile as f16. Granule g covers data cols 8g-4 .. 8g+3
    // (global cols col0+8g-4 ..): two aligned float4 loads -> 4 cvt_pkrtz
    // -> one 16B LDS granule. Halo granules from neighbor tiles are
    // in-bounds except at the image edge (per-load bounds check).
    #pragma unroll
    for (int it = 0; it < 5; ++it) {
        int s = tid + it * 256;
        if (s < NSLOT) {
            int r  = s / NG;
            int c8 = s - r * NG;
            int gr = row0 - 3 + r;
            int gc = col0 + c8 * 8 - 4;
            float4 f0 = make_float4(0.f, 0.f, 0.f, 0.f);
            float4 f1 = make_float4(0.f, 0.f, 0.f, 0.f);
            if ((unsigned)gr < (unsigned)HW) {
                const float* rowp = xp + (gr << 8);
                if ((unsigned)gc       <= (unsigned)(HW - 4)) f0 = *(const float4*)(rowp + gc);
                if ((unsigned)(gc + 4) <= (unsigned)(HW - 4)) f1 = *(const float4*)(rowp + gc + 4);
            }
            U32H2 w0, w1, w2, w3;
            w0.h = __builtin_amdgcn_cvt_pkrtz(f0.x, f0.y);
            w1.h = __builtin_amdgcn_cvt_pkrtz(f0.z, f0.w);
            w2.h = __builtin_amdgcn_cvt_pkrtz(f1.x, f1.y);
            w3.h = __builtin_amdgcn_cvt_pkrtz(f1.z, f1.w);
            uint4 g; g.x = w0.i; g.y = w1.i; g.z = w2.i; g.w = w3.i;
            smemU4[r * NGP + c8] = g;
        }
    }
    __syncthreads();

    // Thread: out rows 4*ty+{0..3}, cols 8*tx..8*tx+7.
    // Window h[0..15] = data cols 8tx-4 .. 8tx+11 = granules tx, tx+1,
    // over input rows 4*ty .. 4*ty+9.
    float acc[4][8];
    #pragma unroll
    for (int j = 0; j < 4; ++j)
        #pragma unroll
        for (int c = 0; c < 8; ++c) acc[j][c] = 0.f;

    #pragma unroll
    for (int rr = 0; rr < 10; ++rr) {
        const int lr = 4 * ty + rr;
        const uint4 A = smemU4[lr * NGP + tx];
        const uint4 B = smemU4[lr * NGP + tx + 1];
        unsigned us[8] = {A.x, A.y, A.z, A.w, B.x, B.y, B.z, B.w};
        unsigned vs[7];
        #pragma unroll
        for (int k = 0; k < 7; ++k)
            vs[k] = __builtin_amdgcn_alignbit(us[k + 1], us[k], 16);

        // input row lr feeds output row j with kernel row p = rr - j
        #pragma unroll
        for (int j = 0; j < 4; ++j) {
            const int p = rr - j;
            if (p >= 0 && p <= 6) {          // compile-time after unroll
                #pragma unroll
                for (int t = 0; t < 4; ++t) {
                    const unsigned w = wA[p][t];
                    #pragma unroll
                    for (int cc = 0; cc < 4; ++cc) {
                        acc[j][2 * cc]     = fdot2u(vs[cc + t],     w, acc[j][2 * cc]);
                        acc[j][2 * cc + 1] = fdot2u(us[cc + 1 + t], w, acc[j][2 * cc + 1]);
                    }
                }
            }
        }
    }

    #pragma unroll
    for (int j = 0; j < 4; ++j) {
        float4 o0, o1;
        o0.x = mish_f(acc[j][0]); o0.y = mish_f(acc[j][1]);
        o0.z = mish_f(acc[j][2]); o0.w = mish_f(acc[j][3]);
        o1.x = mish_f(acc[j][4]); o1.y = mish_f(acc[j][5]);
        o1.z = mish_f(acc[j][6]); o1.w = mish_f(acc[j][7]);
        float* dst = op + (row0 + 4 * ty + j) * HW + col0 + tx * 8;
        *(float4*)(dst)     = o0;
        *(float4*)(dst + 4) = o1;
    }
}

extern "C" void kernel_launch(void* const* d_in, const int* in_sizes, int n_in,
                              void* d_out, int out_size, void* d_ws, size_t ws_size,
                              hipStream_t stream) {
    const float* x = (const float*)d_in[0];
    const float* k = (const float*)d_in[1];
    float* out = (float*)d_out;

    dim3 grid(HW / TILE_W, HW / TILE_H, 16 * 64);  // 4 x 2 x 1024
    dim3 block(256);
    dwconv7_mish_kernel<<<grid, block, 0, stream>>>(x, k, out);
}

// Round 10
// 146.117 us; speedup vs baseline: 1.2774x; 1.2774x over previous
//
#include <hip/hip_runtime.h>

// Depthwise 7x7 true-convolution (flipped kernel, SAME zero pad) + mish,
// via MFMA (v_mfma_f32_16x16x32_f16) with a banded-Toeplitz weight matrix.
//
// Per 16x16 output tile (rows i, cols j) and kernel row p:
//   C[i,j] += sum_k A_p[i,k] * B_p[k,j]
//   A_p[i,k] = Xf16[r0+i+p-3, c0+16t-8+k]      (staged LDS tile, k=0..31)
//   B_p[k,j] = W'[p][k-j-5] (0 outside 0..6),  W'[p][q] = kern[6-p][6-q]
// => C[i,j] = sum_{p,q} W'[p][q] X[r0+i+p-3, c0+16t+j+q-3]  (exact taps).
// 7 MFMAs per tile; weights' banded matrices (7 x 16x32 f16, 7 KB) built
// once per block in LDS. Input tile 70 rows x 80 f32 -> f16 LDS, pitch 88
// halfs (176 B): A-frag ds_read_b128 banks = (44*(l&15) + 4*(l>>4)) mod 32
// -> uniform 8 words/bank = b128 hardware minimum. All K-window reads are
// 16B aligned because the window origin is c0-8 (multiple of 8 floats).
// Block = 256 thr = 4 waves; block tile 64x64 (wave w: rows 16w..16w+15,
// 4 col-subtiles). MFMA C layout (m89): col = lane&15, row = (lane>>4)*4+reg.
// Mish epilogue in f32 on VALU; fp32 accumulation throughout.

#define HW 256
#define PITCH 88           // halfs per LDS input row
#define LROWS 70           // 64 + 6 halo
#define NSTG (LROWS * 20)  // 20 aligned float4 granules per row

typedef _Float16 f16x8 __attribute__((ext_vector_type(8)));
typedef float    f32x4 __attribute__((ext_vector_type(4)));
typedef __fp16   h2    __attribute__((ext_vector_type(2)));
union U32H2 { unsigned u; h2 h; };
union BFU   { uint4 u; f16x8 h; };

__device__ __forceinline__ float mish_f(float y) {
    float t = __expf(y);            // inf-safe: d -> inf -> 2/d -> 0 -> y*1
    float u = 1.0f + t;
    float d = __fmaf_rn(u, u, 1.0f);
    return y * (1.0f - __fdividef(2.0f, d));
}

__global__ __launch_bounds__(256)
void dwconv7_mish_mfma(const float* __restrict__ x,
                       const float* __restrict__ kern,
                       float* __restrict__ out) {
    __shared__ __align__(16) _Float16 lds_in[LROWS * PITCH];  // 12,320 B
    __shared__ __align__(16) unsigned lds_B[7 * 256];         //  7,168 B

    const int tid = threadIdx.x;
    const int c0 = blockIdx.x * 64;
    const int r0 = blockIdx.y * 64;
    const int plane = blockIdx.z;

    const float* __restrict__ xp = x + (size_t)plane * (HW * HW);
    float* __restrict__ op = out + (size_t)plane * (HW * HW);

    // Flipped kernel in SGPRs: kf[p*7+q] = kern[6-p][6-q]
    float kf[49];
    #pragma unroll
    for (int i = 0; i < 49; ++i) {
        int p = i / 7, q = i - p * 7;
        kf[i] = __int_as_float(__builtin_amdgcn_readfirstlane(
                    __float_as_int(kern[(6 - p) * 7 + (6 - q)])));
    }

    // Build banded-Toeplitz B_p[16][32] f16 (row j, col k), word-linear:
    // word idx = p*256 + j*16 + kw  (kw = k/2). Exactly 7 x 256 words.
    #pragma unroll
    for (int p = 0; p < 7; ++p) {
        const int j  = tid >> 4;
        const int kw = tid & 15;
        const int d0 = 2 * kw - j - 5;     // q for k=2kw
        const int d1 = d0 + 1;             // q for k=2kw+1
        float v0 = 0.f, v1 = 0.f;
        #pragma unroll
        for (int q = 0; q < 7; ++q) {
            v0 = (d0 == q) ? kf[p * 7 + q] : v0;
            v1 = (d1 == q) ? kf[p * 7 + q] : v1;
        }
        U32H2 u; u.h = __builtin_amdgcn_cvt_pkrtz(v0, v1);
        lds_B[p * 256 + tid] = u.u;
    }

    // Stage input tile as f16: rows r0-3 .. r0+66, cols c0-8 .. c0+71
    // (tc = 0..79; pitch pad 80..87 never read). Aligned float4 loads;
    // out-of-image granules become zeros (correct SAME padding).
    #pragma unroll
    for (int it = 0; it < 6; ++it) {
        int s = tid + it * 256;
        if (s < NSTG) {
            int tr = s / 20;
            int g  = s - tr * 20;
            int gr = r0 - 3 + tr;
            int gc = c0 - 8 + 4 * g;
            float4 f = make_float4(0.f, 0.f, 0.f, 0.f);
            if ((unsigned)gr < (unsigned)HW && (unsigned)gc <= (unsigned)(HW - 4)) {
                f = *(const float4*)(xp + (gr << 8) + gc);
            }
            U32H2 a, b;
            a.h = __builtin_amdgcn_cvt_pkrtz(f.x, f.y);
            b.h = __builtin_amdgcn_cvt_pkrtz(f.z, f.w);
            ((uint2*)lds_in)[tr * 22 + g] = make_uint2(a.u, b.u);
        }
    }
    __syncthreads();

    const int lane = tid & 63;
    const int w    = tid >> 6;          // wave: rows r0+16w .. +15
    const int lrow = lane & 15;
    const int lk   = lane >> 4;

    // B fragments: B[k = lk*8+e, j = lrow] -> contiguous 16 B per lane.
    f16x8 bfrag[7];
    #pragma unroll
    for (int p = 0; p < 7; ++p) {
        BFU bu;
        bu.u = *((const uint4*)lds_B + (p * 64 + lrow * 4 + lk));
        bfrag[p] = bu.h;
    }

    // 4 col-subtiles of 16; A[i = lrow, k = lk*8+e] from LDS.
    #pragma unroll
    for (int t = 0; t < 4; ++t) {
        f32x4 acc = {0.f, 0.f, 0.f, 0.f};
        #pragma unroll
        for (int p = 0; p < 7; ++p) {
            f16x8 a = *(const f16x8*)(lds_in +
                        (16 * w + lrow + p) * PITCH + 16 * t + 8 * lk);
            acc = __builtin_amdgcn_mfma_f32_16x16x32_f16(a, bfrag[p], acc,
                                                         0, 0, 0);
        }
        // C: col = lane&15, row = (lane>>4)*4 + reg
        const int col   = c0 + 16 * t + lrow;
        const int rbase = r0 + 16 * w + 4 * lk;
        op[(rbase + 0) * HW + col] = mish_f(acc[0]);
        op[(rbase + 1) * HW + col] = mish_f(acc[1]);
        op[(rbase + 2) * HW + col] = mish_f(acc[2]);
        op[(rbase + 3) * HW + col] = mish_f(acc[3]);
    }
}

extern "C" void kernel_launch(void* const* d_in, const int* in_sizes, int n_in,
                              void* d_out, int out_size, void* d_ws, size_t ws_size,
                              hipStream_t stream) {
    const float* x = (const float*)d_in[0];
    const float* k = (const float*)d_in[1];
    float* out = (float*)d_out;

    dim3 grid(HW / 64, HW / 64, 16 * 64);  // 4 x 4 x 1024
    dim3 block(256);
    dwconv7_mish_mfma<<<grid, block, 0, stream>>>(x, k, out);
}

// Round 11
// 137.826 us; speedup vs baseline: 1.3542x; 1.0602x over previous
//
#include <hip/hip_runtime.h>

// Depthwise 7x7 true-convolution (flipped kernel, SAME zero pad) + mish,
// via MFMA (v_mfma_f32_16x16x32_f16) with banded-Toeplitz weight matrices.
// Round-11: same verified MFMA core as round-10, restructured for latency:
//  - 8 tiles (64x64) of one plane per block (grid 2048): kernel load,
//    B-matrix build, bfrag setup amortized 8x.
//  - double-buffered LDS staging: tile t+1's global loads + f16 cvt issue
//    BEFORE tile t's compute (MFMA+mish+store), ds_write after, one barrier
//    per tile -> staging latency hides under compute (T14 pattern).
//  - per-thread staging decomposition precomputed once.
//
// Math per 16x16 output subtile, kernel row p:
//   C[i,j] += A_p[i,:] x B_p[:,j],  A_p[i,k] = Xf16[r0+i+p-3, c0-8+16t+k],
//   B_p[k,j] = W'[p][k-j-5] (banded), W'[p][q] = kern[6-p][6-q].
// MFMA C layout (m89): col = lane&15, row = (lane>>4)*4 + reg.

#define HW 256
#define PITCH 88           // halfs per LDS input row
#define LROWS 70           // 64 + 6 halo
#define NSTG 1400          // 70 rows * 20 float4 granules
#define TPB 8              // tiles per block (half a plane)
#define BUFU2 (LROWS * 22) // uint2 slots per buffer (22 per row = 88 halfs)

typedef _Float16 f16x8 __attribute__((ext_vector_type(8)));
typedef float    f32x4 __attribute__((ext_vector_type(4)));
typedef __fp16   h2    __attribute__((ext_vector_type(2)));
union U32H2 { unsigned u; h2 h; };
union BFU   { uint4 u; f16x8 h; };

__device__ __forceinline__ float mish_f(float y) {
    float t = __expf(y);            // inf-safe: d -> inf -> 2/d -> 0 -> y*1
    float u = 1.0f + t;
    float d = __fmaf_rn(u, u, 1.0f);
    return y * (1.0f - __fdividef(2.0f, d));
}

__global__ __launch_bounds__(256)
void dwconv7_mish_mfma2(const float* __restrict__ x,
                        const float* __restrict__ kern,
                        float* __restrict__ out) {
    __shared__ __align__(16) _Float16 lds_in[2][LROWS * PITCH]; // 2 x 12320 B
    __shared__ __align__(16) unsigned lds_B[7 * 256];           // 7168 B

    const int tid = threadIdx.x;
    const int bid = blockIdx.x;
    const int plane = bid >> 1;          // 2 blocks per plane
    const int sbase = (bid & 1) << 3;    // tile slot 0..15: c0=(s&3)*64, r0=(s>>2)*64

    const float* __restrict__ xp = x + (size_t)plane * (HW * HW);
    float* __restrict__ op = out + (size_t)plane * (HW * HW);

    // Flipped kernel in SGPRs: kf[p*7+q] = kern[6-p][6-q]
    float kf[49];
    #pragma unroll
    for (int i = 0; i < 49; ++i) {
        int p = i / 7, q = i - p * 7;
        kf[i] = __int_as_float(__builtin_amdgcn_readfirstlane(
                    __float_as_int(kern[(6 - p) * 7 + (6 - q)])));
    }

    // Banded-Toeplitz B_p[16][32] f16, word idx = p*256 + j*16 + k/2.
    {
        const int j  = tid >> 4;
        const int kw = tid & 15;
        #pragma unroll
        for (int p = 0; p < 7; ++p) {
            const int d0 = 2 * kw - j - 5;
            const int d1 = d0 + 1;
            float v0 = 0.f, v1 = 0.f;
            #pragma unroll
            for (int q = 0; q < 7; ++q) {
                v0 = (d0 == q) ? kf[p * 7 + q] : v0;
                v1 = (d1 == q) ? kf[p * 7 + q] : v1;
            }
            U32H2 u; u.h = __builtin_amdgcn_cvt_pkrtz(v0, v1);
            lds_B[p * 256 + tid] = u.u;
        }
    }

    // Precompute per-thread staging decomposition (static per it):
    // granule idx = tid + 256*it -> r = idx/20, g = idx%20.
    int ro_[6], co_[6], lo_[6];          // row off (-3+r), col off (-8+4g), lds slot
    #pragma unroll
    for (int it = 0; it < 6; ++it) {
        int idx = tid + it * 256;
        int r = idx / 20, g = idx - 20 * r;
        ro_[it] = r - 3;
        co_[it] = 4 * g - 8;
        lo_[it] = r * 22 + g;
    }

    uint2 rst[6];

    // Prologue: stage tile sbase into buf0.
    {
        const int s = sbase;
        const int c0 = (s & 3) << 6, r0 = (s >> 2) << 6;
        #pragma unroll
        for (int it = 0; it < 6; ++it) {
            if (tid + it * 256 < NSTG) {
                int gr = r0 + ro_[it], gc = c0 + co_[it];
                float4 f = make_float4(0.f, 0.f, 0.f, 0.f);
                if ((unsigned)gr < (unsigned)HW && (unsigned)gc <= (unsigned)(HW - 4))
                    f = *(const float4*)(xp + (gr << 8) + gc);
                U32H2 a, b;
                a.h = __builtin_amdgcn_cvt_pkrtz(f.x, f.y);
                b.h = __builtin_amdgcn_cvt_pkrtz(f.z, f.w);
                ((uint2*)lds_in[0])[lo_[it]] = make_uint2(a.u, b.u);
            }
        }
    }
    __syncthreads();

    const int lane = tid & 63;
    const int w    = tid >> 6;           // wave: tile rows 16w..16w+15
    const int lrow = lane & 15;
    const int lk   = lane >> 4;

    // B fragments: B[k=lk*8+e, j=lrow], contiguous 16 B per lane.
    f16x8 bfrag[7];
    #pragma unroll
    for (int p = 0; p < 7; ++p) {
        BFU bu;
        bu.u = ((const uint4*)lds_B)[p * 64 + lrow * 4 + lk];
        bfrag[p] = bu.h;
    }

    #pragma unroll 1
    for (int t = 0; t < TPB; ++t) {
        const int s  = sbase + t;
        const int c0 = (s & 3) << 6, r0 = (s >> 2) << 6;

        // 1) issue next tile's global loads + cvt into registers
        if (t + 1 < TPB) {
            const int s2 = sbase + t + 1;
            const int c2 = (s2 & 3) << 6, r2 = (s2 >> 2) << 6;
            #pragma unroll
            for (int it = 0; it < 6; ++it) {
                if (tid + it * 256 < NSTG) {
                    int gr = r2 + ro_[it], gc = c2 + co_[it];
                    float4 f = make_float4(0.f, 0.f, 0.f, 0.f);
                    if ((unsigned)gr < (unsigned)HW && (unsigned)gc <= (unsigned)(HW - 4))
                        f = *(const float4*)(xp + (gr << 8) + gc);
                    U32H2 a, b;
                    a.h = __builtin_amdgcn_cvt_pkrtz(f.x, f.y);
                    b.h = __builtin_amdgcn_cvt_pkrtz(f.z, f.w);
                    rst[it] = make_uint2(a.u, b.u);
                }
            }
        }

        // 2) compute current tile from lds_in[t&1]
        const _Float16* bufp = lds_in[t & 1];
        #pragma unroll
        for (int t4 = 0; t4 < 4; ++t4) {
            f32x4 acc = {0.f, 0.f, 0.f, 0.f};
            #pragma unroll
            for (int p = 0; p < 7; ++p) {
                f16x8 a = *(const f16x8*)(bufp +
                            (16 * w + lrow + p) * PITCH + 16 * t4 + 8 * lk);
                acc = __builtin_amdgcn_mfma_f32_16x16x32_f16(a, bfrag[p], acc,
                                                             0, 0, 0);
            }
            const int col   = c0 + 16 * t4 + lrow;
            const int rbase = r0 + 16 * w + 4 * lk;
            op[(rbase + 0) * HW + col] = mish_f(acc[0]);
            op[(rbase + 1) * HW + col] = mish_f(acc[1]);
            op[(rbase + 2) * HW + col] = mish_f(acc[2]);
            op[(rbase + 3) * HW + col] = mish_f(acc[3]);
        }

        // 3) write staged regs into the other buffer
        if (t + 1 < TPB) {
            #pragma unroll
            for (int it = 0; it < 6; ++it) {
                if (tid + it * 256 < NSTG) {
                    ((uint2*)lds_in[(t + 1) & 1])[lo_[it]] = rst[it];
                }
            }
        }
        // 4) one barrier per tile: next compute may read the fresh buffer;
        //    next iteration's ds_write targets the buffer read in step 2,
        //    which all waves have finished (they passed this barrier).
        __syncthreads();
    }
}

extern "C" void kernel_launch(void* const* d_in, const int* in_sizes, int n_in,
                              void* d_out, int out_size, void* d_ws, size_t ws_size,
                              hipStream_t stream) {
    const float* x = (const float*)d_in[0];
    const float* k = (const float*)d_in[1];
    float* out = (float*)d_out;

    dim3 grid(2 * 16 * 64, 1, 1);   // 2048 blocks: 2 per plane
    dim3 block(256);
    dwconv7_mish_mfma2<<<grid, block, 0, stream>>>(x, k, out);
}